// Round 13
// baseline (125.847 us; speedup 1.0000x reference)
//
#include <hip/hip_runtime.h>
#include <hip/hip_bf16.h>

#define NVOX 100000
#define CIN 32
#define COUT 32
#define KOFF 27
#define NTILE 6250            // NVOX / 16 exactly
#define KDEPTH 3              // gather prefetch depth per stream

typedef __attribute__((ext_vector_type(8))) short short8;
typedef __attribute__((ext_vector_type(4))) float float4v;

// fp32 -> bf16 round-to-nearest-even (finite inputs)
__device__ __forceinline__ short f2bf(float x) {
    union { float f; unsigned u; } v; v.f = x;
    unsigned u = v.u;
    u += 0x7FFFu + ((u >> 16) & 1u);
    return (short)(u >> 16);
}

#define FEAT_BLOCKS 3126      // ceil((NVOX+1)*CIN/4 / 256)

// ---- fused pre-pass: features fp32->bf16 (+zero row) AND weight B-fragments ----
__global__ __launch_bounds__(256) void cvt_kernel(
    const float* __restrict__ feat, const float* __restrict__ weight,
    unsigned short* __restrict__ fbf, short8* __restrict__ wfrag)
{
    if (blockIdx.x < FEAT_BLOCKS) {
        int i = (blockIdx.x * 256 + threadIdx.x) * 4;
        if (i < NVOX * CIN) {
            float4v f = *(const float4v*)(feat + i);
            short s[4] = { f2bf(f.x), f2bf(f.y), f2bf(f.z), f2bf(f.w) };
            *(ulonglong1*)(fbf + i) = *(ulonglong1*)s;
        } else if (i < (NVOX + 1) * CIN) {
            short s[4] = { 0, 0, 0, 0 };           // zero row for masked gathers
            *(ulonglong1*)(fbf + i) = *(ulonglong1*)s;
        }
    } else {
        // wfrag[k*128 + t*64 + ln][j] = W[k][ci=(ln>>4)*8+j][co=t*16+(ln&15)]
        int g = (blockIdx.x - FEAT_BLOCKS) * 256 + threadIdx.x;
        if (g >= KOFF * 2 * 64) return;
        int k   = g >> 7;
        int rem = g & 127;
        int t   = rem >> 6;
        int ln  = rem & 63;
        int co  = t * 16 + (ln & 15);
        int cib = (ln >> 4) * 8;
        const float* wp = weight + (k * CIN + cib) * COUT + co;
        short8 b;
#pragma unroll
        for (int j = 0; j < 8; ++j) b[j] = f2bf(wp[j * COUT]);
        wfrag[g] = b;
    }
}

// Two tiles (A/B streams) per wave: shared weight ds_reads, doubled gather MLP.
// amdgpu_waves_per_eu(4,4): pin exactly 4 waves/EU -> full 128-VGPR budget,
// prevents the allocator from targeting 64 VGPR and spilling (R12 failure).
__global__ __launch_bounds__(512)
__attribute__((amdgpu_waves_per_eu(4, 4)))
void subm_conv_kernel(
    const unsigned short* __restrict__ fbf,   // bf16 features [N+1,32] (ws)
    const short8* __restrict__ wfrag,         // bf16 B-fragments (ws)
    const float* __restrict__ bias,           // fp32 [32]
    const int* __restrict__ nbr_idx,          // int32 [N,27]
    const int* __restrict__ nbr_mask,         // bool -> int32 [N,27]
    float* __restrict__ out)                  // fp32 [N,32]
{
    __shared__ short8 wlds[KOFF * 2 * 64];    // 55,296 B; reused for store transpose

    const int tid  = threadIdx.x;
    const int lane = tid & 63;
    const int wave = tid >> 6;                 // 0..7
    const int m    = lane & 15;
    const int quad = lane >> 4;

    const int tA = (blockIdx.x * 8 + wave) * 2;    // two tiles per wave
    const int tB = tA + 1;
    const bool tvA = tA < NTILE;
    const bool tvB = tB < NTILE;

    int vA = tA * 16 + m; if (vA > NVOX - 1) vA = NVOX - 1;   // clamp loads
    int vB = tB * 16 + m; if (vB > NVOX - 1) vB = NVOX - 1;
    const int baseA = vA * KOFF;
    const int baseB = vB * KOFF;

    // metadata: both tiles' idx+mask issued up front, folded to byte offsets
    int encA[KOFF], encB[KOFF];
#pragma unroll
    for (int k = 0; k < KOFF; ++k)
        encA[k] = (nbr_mask[baseA + k] ? nbr_idx[baseA + k] : NVOX) << 6;
#pragma unroll
    for (int k = 0; k < KOFF; ++k)
        encB[k] = (nbr_mask[baseB + k] ? nbr_idx[baseB + k] : NVOX) << 6;

    for (int g = tid; g < KOFF * 2 * 64; g += 512) wlds[g] = wfrag[g];
    __syncthreads();

    float4v accA0 = {0.f, 0.f, 0.f, 0.f};
    float4v accA1 = {0.f, 0.f, 0.f, 0.f};
    float4v accB0 = {0.f, 0.f, 0.f, 0.f};
    float4v accB1 = {0.f, 0.f, 0.f, 0.f};

    const char* fb   = (const char*)fbf;
    const int   boff = quad * 16;              // byte offset of A-frag in row

    // ---- dual-stream rotating gather pipeline, fully unrolled ----
    short8 abufA[KDEPTH], abufB[KDEPTH];
#pragma unroll
    for (int k = 0; k < KDEPTH; ++k) {
        abufA[k] = *(const short8*)(fb + (size_t)(unsigned)encA[k] + boff);
        abufB[k] = *(const short8*)(fb + (size_t)(unsigned)encB[k] + boff);
    }

#pragma unroll
    for (int k = 0; k < KOFF; ++k) {
        const int slot = k % KDEPTH;
        short8 aA = abufA[slot];
        short8 aB = abufB[slot];
        if (k + KDEPTH < KOFF) {
            abufA[slot] = *(const short8*)(fb + (size_t)(unsigned)encA[k + KDEPTH] + boff);
            abufB[slot] = *(const short8*)(fb + (size_t)(unsigned)encB[k + KDEPTH] + boff);
        }

        short8 wb0 = wlds[k * 128 + lane];     // shared by both tile streams
        short8 wb1 = wlds[k * 128 + 64 + lane];
        accA0 = __builtin_amdgcn_mfma_f32_16x16x32_bf16(aA, wb0, accA0, 0, 0, 0);
        accA1 = __builtin_amdgcn_mfma_f32_16x16x32_bf16(aA, wb1, accA1, 0, 0, 0);
        accB0 = __builtin_amdgcn_mfma_f32_16x16x32_bf16(aB, wb0, accB0, 0, 0, 0);
        accB1 = __builtin_amdgcn_mfma_f32_16x16x32_bf16(aB, wb1, accB1, 0, 0, 0);
    }

    // ---- coalesced epilogue via LDS transpose (R10-proven pattern) ----
    __syncthreads();                           // all waves done reading weights
    float* tbA = (float*)wlds + wave * 1152;   // 2 disjoint 16x36 tiles per wave
    float* tbB = tbA + 576;

    const float bs0 = bias[m];
    const float bs1 = bias[16 + m];
    // C/D layout: col (cout) = lane&15, row (voxel) = quad*4 + reg
    if (tvA) {
#pragma unroll
        for (int r = 0; r < 4; ++r) {
            tbA[(quad * 4 + r) * 36 + m]      = accA0[r] + bs0;
            tbA[(quad * 4 + r) * 36 + 16 + m] = accA1[r] + bs1;
        }
    }
    if (tvB) {
#pragma unroll
        for (int r = 0; r < 4; ++r) {
            tbB[(quad * 4 + r) * 36 + m]      = accB0[r] + bs0;
            tbB[(quad * 4 + r) * 36 + 16 + m] = accB1[r] + bs1;
        }
    }
    if (tvA) {
#pragma unroll
        for (int p = 0; p < 2; ++p) {
            int flat = p * 64 + lane;
            int row  = flat >> 3;              // 8 lanes per 128B output row
            int ch   = flat & 7;
            float4v val = *(const float4v*)(tbA + row * 36 + ch * 4);
            *(float4v*)(out + (size_t)(tA * 16 + row) * COUT + ch * 4) = val;
        }
    }
    if (tvB) {
#pragma unroll
        for (int p = 0; p < 2; ++p) {
            int flat = p * 64 + lane;
            int row  = flat >> 3;
            int ch   = flat & 7;
            float4v val = *(const float4v*)(tbB + row * 36 + ch * 4);
            *(float4v*)(out + (size_t)(tB * 16 + row) * COUT + ch * 4) = val;
        }
    }
}

extern "C" void kernel_launch(void* const* d_in, const int* in_sizes, int n_in,
                              void* d_out, int out_size, void* d_ws, size_t ws_size,
                              hipStream_t stream) {
    const float* feat = (const float*)d_in[0];
    const float* wgt  = (const float*)d_in[1];
    const float* bias = (const float*)d_in[2];
    const int*   nidx = (const int*)d_in[3];
    const int*   nmsk = (const int*)d_in[4];
    float*       out  = (float*)d_out;

    char* ws = (char*)d_ws;
    unsigned short* fbf   = (unsigned short*)ws;                 // 6,400,064 B
    short8*         wfrag = (short8*)(ws + 6400128);             //    55,296 B

    const int wgt_blocks = (KOFF * 2 * 64 + 255) / 256;          // 14
    cvt_kernel<<<FEAT_BLOCKS + wgt_blocks, 256, 0, stream>>>(feat, wgt, fbf, wfrag);

    const int block = 512;                         // 8 waves x 2 tiles = 256 voxels/block
    const int grid  = (NTILE + 15) / 16;           // 391
    subm_conv_kernel<<<grid, block, 0, stream>>>(fbf, wfrag, bias, nidx, nmsk, out);
}

// Round 14
// 108.838 us; speedup vs baseline: 1.1563x; 1.1563x over previous
//
#include <hip/hip_runtime.h>
#include <hip/hip_bf16.h>

#define NVOX 100000
#define CIN 32
#define COUT 32
#define KOFF 27
#define NT32 3125             // NVOX / 32 exactly
#define KD 3                  // gather prefetch depth

typedef __attribute__((ext_vector_type(8)))  short  short8;
typedef __attribute__((ext_vector_type(4)))  float  float4v;
typedef __attribute__((ext_vector_type(16))) float  float16v;

// fp32 -> bf16 round-to-nearest-even (finite inputs)
__device__ __forceinline__ short f2bf(float x) {
    union { float f; unsigned u; } v; v.f = x;
    unsigned u = v.u;
    u += 0x7FFFu + ((u >> 16) & 1u);
    return (short)(u >> 16);
}

#define FEAT_BLOCKS 3126      // ceil((NVOX+1)*CIN/4 / 256)

// ---- fused pre-pass: features fp32->bf16 (+zero row) AND 32x32 B-fragments ----
__global__ __launch_bounds__(256) void cvt_kernel(
    const float* __restrict__ feat, const float* __restrict__ weight,
    unsigned short* __restrict__ fbf, short8* __restrict__ wfrag)
{
    if (blockIdx.x < FEAT_BLOCKS) {
        int i = (blockIdx.x * 256 + threadIdx.x) * 4;
        if (i < NVOX * CIN) {
            float4v f = *(const float4v*)(feat + i);
            short s[4] = { f2bf(f.x), f2bf(f.y), f2bf(f.z), f2bf(f.w) };
            *(ulonglong1*)(fbf + i) = *(ulonglong1*)s;
        } else if (i < (NVOX + 1) * CIN) {
            short s[4] = { 0, 0, 0, 0 };           // zero row for masked gathers
            *(ulonglong1*)(fbf + i) = *(ulonglong1*)s;
        }
    } else {
        // 32x32 B-operand: wfrag[k*128 + h*64 + ln][j] =
        //   W[k][ci = h*16 + (ln>>5)*8 + j][co = ln&31]
        int g = (blockIdx.x - FEAT_BLOCKS) * 256 + threadIdx.x;
        if (g >= KOFF * 2 * 64) return;
        int k   = g >> 7;
        int rem = g & 127;
        int h   = rem >> 6;                        // ci half (0: 0-15, 1: 16-31)
        int ln  = rem & 63;
        int co  = ln & 31;
        int cib = h * 16 + ((ln >> 5) * 8);
        const float* wp = weight + (k * CIN + cib) * COUT + co;
        short8 b;
#pragma unroll
        for (int j = 0; j < 8; ++j) b[j] = f2bf(wp[j * COUT]);
        wfrag[g] = b;
    }
}

// One wave = 32 voxels x 32 cout via mfma_f32_32x32x16_bf16 (2 MFMA per offset,
// K-accumulated). Halves DS-pipe cost and wave count per voxel vs 16x16 tiles.
__global__
__attribute__((amdgpu_flat_work_group_size(256, 256), amdgpu_waves_per_eu(2, 2)))
void subm_conv_kernel(
    const unsigned short* __restrict__ fbf,   // bf16 features [N+1,32] (ws)
    const short8* __restrict__ wfrag,         // bf16 B-fragments (ws)
    const float* __restrict__ bias,           // fp32 [32]
    const int* __restrict__ nbr_idx,          // int32 [N,27]
    const int* __restrict__ nbr_mask,         // bool -> int32 [N,27]
    float* __restrict__ out)                  // fp32 [N,32]
{
    __shared__ short8 wlds[KOFF * 2 * 64];    // 55,296 B; reused for store transpose

    const int tid  = threadIdx.x;
    const int lane = tid & 63;
    const int wave = tid >> 6;                 // 0..3
    const int r32  = lane & 31;                // voxel row within tile
    const int half = lane >> 5;                // ci-half owner
    const int tile = blockIdx.x * 4 + wave;    // 32 voxels per tile
    const bool tv  = tile < NT32;

    const int v    = tv ? (tile * 32 + r32) : 0;
    const int base = v * KOFF;

    // metadata: 27 idx + 27 masks up front (R5/R10-proven), folded to byte offsets
    int enc[KOFF];
    if (tv) {
#pragma unroll
        for (int k = 0; k < KOFF; ++k) enc[k] = nbr_idx[base + k];
        int mok[KOFF];
#pragma unroll
        for (int k = 0; k < KOFF; ++k) mok[k] = nbr_mask[base + k];
#pragma unroll
        for (int k = 0; k < KOFF; ++k) enc[k] = (mok[k] ? enc[k] : NVOX) << 6;
    } else {
#pragma unroll
        for (int k = 0; k < KOFF; ++k) enc[k] = NVOX << 6;
    }

    for (int g = tid; g < KOFF * 2 * 64; g += 256) wlds[g] = wfrag[g];
    __syncthreads();

    float16v acc = {};

    const char* fb = (const char*)fbf;
    const int  b0 = half * 16;                 // A-frag byte offset, ci-half 0
    const int  b1 = 32 + half * 16;            // A-frag byte offset, ci-half 1

    // ---- depth-3 rotating gather pipeline (pairs), fully unrolled ----
    short8 pa[KD], pb[KD];
#pragma unroll
    for (int k = 0; k < KD; ++k) {
        const char* p = fb + (size_t)(unsigned)enc[k];
        pa[k] = *(const short8*)(p + b0);
        pb[k] = *(const short8*)(p + b1);
    }

#pragma unroll
    for (int k = 0; k < KOFF; ++k) {
        const int slot = k % KD;
        short8 a0 = pa[slot];
        short8 a1 = pb[slot];
        if (k + KD < KOFF) {
            const char* p = fb + (size_t)(unsigned)enc[k + KD];
            pa[slot] = *(const short8*)(p + b0);
            pb[slot] = *(const short8*)(p + b1);
        }

        short8 wb0 = wlds[k * 128 + lane];         // ci 0-15
        short8 wb1 = wlds[k * 128 + 64 + lane];    // ci 16-31
        acc = __builtin_amdgcn_mfma_f32_32x32x16_bf16(a0, wb0, acc, 0, 0, 0);
        acc = __builtin_amdgcn_mfma_f32_32x32x16_bf16(a1, wb1, acc, 0, 0, 0);
    }

    // ---- coalesced epilogue via LDS transpose ----
    // C/D (verified m74/m101): col = lane&31, row = (r&3) + 8*(r>>2) + 4*half
    __syncthreads();                           // weight reads done; reuse wlds
    float* tb = (float*)wlds + wave * (32 * 36);

    const float bs = bias[r32];                // col = r32 for this lane
    if (tv) {
#pragma unroll
        for (int r = 0; r < 16; ++r) {
            int row = (r & 3) + 8 * (r >> 2) + 4 * half;
            tb[row * 36 + r32] = acc[r] + bs;
        }
#pragma unroll
        for (int p = 0; p < 4; ++p) {
            int flat = p * 64 + lane;          // 0..255
            int row  = flat >> 3;              // 8 lanes per 128B output row
            int ch   = flat & 7;
            float4v val = *(const float4v*)(tb + row * 36 + ch * 4);
            *(float4v*)(out + (size_t)(tile * 32 + row) * COUT + ch * 4) = val;
        }
    }
}

extern "C" void kernel_launch(void* const* d_in, const int* in_sizes, int n_in,
                              void* d_out, int out_size, void* d_ws, size_t ws_size,
                              hipStream_t stream) {
    const float* feat = (const float*)d_in[0];
    const float* wgt  = (const float*)d_in[1];
    const float* bias = (const float*)d_in[2];
    const int*   nidx = (const int*)d_in[3];
    const int*   nmsk = (const int*)d_in[4];
    float*       out  = (float*)d_out;

    char* ws = (char*)d_ws;
    unsigned short* fbf   = (unsigned short*)ws;                 // 6,400,064 B
    short8*         wfrag = (short8*)(ws + 6400128);             //    55,296 B

    const int wgt_blocks = (KOFF * 2 * 64 + 255) / 256;          // 14
    cvt_kernel<<<FEAT_BLOCKS + wgt_blocks, 256, 0, stream>>>(feat, wgt, fbf, wfrag);

    const int block = 256;                         // 4 waves x 32 voxels = 128 voxels
    const int grid  = (NT32 + 3) / 4;              // 782
    subm_conv_kernel<<<grid, block, 0, stream>>>(fbf, wfrag, bias, nidx, nmsk, out);
}

// Round 15
// 101.020 us; speedup vs baseline: 1.2458x; 1.0774x over previous
//
#include <hip/hip_runtime.h>
#include <hip/hip_bf16.h>

#define NVOX 100000
#define CIN 32
#define COUT 32
#define KOFF 27
#define NTILE 6250            // NVOX / 16 exactly

typedef __attribute__((ext_vector_type(8))) short short8;
typedef __attribute__((ext_vector_type(4))) float float4v;

// fp32 -> bf16 round-to-nearest-even (finite inputs)
__device__ __forceinline__ short f2bf(float x) {
    union { float f; unsigned u; } v; v.f = x;
    unsigned u = v.u;
    u += 0x7FFFu + ((u >> 16) & 1u);
    return (short)(u >> 16);
}

#define FEAT_BLOCKS 3126      // ceil((NVOX+1)*CIN/4 / 256)

// ---- fused pre-pass: features fp32->bf16 (+zero row) AND weight B-fragments ----
__global__ __launch_bounds__(256) void cvt_kernel(
    const float* __restrict__ feat, const float* __restrict__ weight,
    unsigned short* __restrict__ fbf, short8* __restrict__ wfrag)
{
    if (blockIdx.x < FEAT_BLOCKS) {
        int i = (blockIdx.x * 256 + threadIdx.x) * 4;
        if (i < NVOX * CIN) {
            float4v f = *(const float4v*)(feat + i);
            short s[4] = { f2bf(f.x), f2bf(f.y), f2bf(f.z), f2bf(f.w) };
            *(ulonglong1*)(fbf + i) = *(ulonglong1*)s;
        } else if (i < (NVOX + 1) * CIN) {
            short s[4] = { 0, 0, 0, 0 };           // zero row for masked gathers
            *(ulonglong1*)(fbf + i) = *(ulonglong1*)s;
        }
    } else {
        // wfrag[k*128 + t*64 + ln][j] = W[k][ci=(ln>>4)*8+j][co=t*16+(ln&15)]
        int g = (blockIdx.x - FEAT_BLOCKS) * 256 + threadIdx.x;
        if (g >= KOFF * 2 * 64) return;
        int k   = g >> 7;
        int rem = g & 127;
        int t   = rem >> 6;
        int ln  = rem & 63;
        int co  = t * 16 + (ln & 15);
        int cib = (ln >> 4) * 8;
        const float* wp = weight + (k * CIN + cib) * COUT + co;
        short8 b;
#pragma unroll
        for (int j = 0; j < 8; ++j) b[j] = f2bf(wp[j * COUT]);
        wfrag[g] = b;
    }
}

__global__ __launch_bounds__(512, 4) void subm_conv_kernel(
    const unsigned short* __restrict__ fbf,   // bf16 features [N+1,32] (ws)
    const short8* __restrict__ wfrag,         // bf16 B-fragments (ws)
    const float* __restrict__ bias,           // fp32 [32]
    const int* __restrict__ nbr_idx,          // int32 [N,27]
    const int* __restrict__ nbr_mask,         // bool -> int32 [N,27]
    float* __restrict__ out)                  // fp32 [N,32]
{
    __shared__ short8 wlds[KOFF * 2 * 64];    // 55,296 B; reused for store transpose

    // ---- XCD-locality swizzle: consecutive blocks round-robin across 8 XCDs;
    // map each XCD a CONTIGUOUS tile range so its 4 MiB L2 holds the ~2.9 MB
    // feature working set (12,544 voxels + neighbor halo). grid = 784 = 8*98.
    const int b  = blockIdx.x;
    const int sb = (b & 7) * 98 + (b >> 3);    // virtual block id, exact cover

    const int tid  = threadIdx.x;
    const int lane = tid & 63;
    const int wave = tid >> 6;                 // 0..7
    const int m    = lane & 15;
    const int quad = lane >> 4;
    const int tile = sb * 8 + wave;            // 16 voxels per wave
    const bool tv  = tile < NTILE;

    const int v0 = tile * 16;
    int v = tv ? (v0 + m) : 0;                 // clamp loads; stores guarded by tv
    const int base = v * KOFF;

    // metadata: all 27 idx + 27 masks issued up front (R5-proven)
    int enc[KOFF];
#pragma unroll
    for (int k = 0; k < KOFF; ++k) enc[k] = nbr_idx[base + k];
    int mok[KOFF];
#pragma unroll
    for (int k = 0; k < KOFF; ++k) mok[k] = nbr_mask[base + k];
#pragma unroll
    for (int k = 0; k < KOFF; ++k) enc[k] = (mok[k] ? enc[k] : NVOX) << 6;

    for (int g = tid; g < KOFF * 2 * 64; g += 512) wlds[g] = wfrag[g];
    __syncthreads();

    float4v acc0 = {0.f, 0.f, 0.f, 0.f};
    float4v acc1 = {0.f, 0.f, 0.f, 0.f};

    const char* fb   = (const char*)fbf;
    const int   boff = quad * 16;              // byte offset of A-frag in row

    // ---- depth-8 rotating gather pipeline, fully unrolled (R5/R10-proven) ----
    short8 abuf[8];
#pragma unroll
    for (int k = 0; k < 8; ++k)
        abuf[k] = *(const short8*)(fb + (size_t)(unsigned)enc[k] + boff);

#pragma unroll
    for (int k = 0; k < KOFF; ++k) {
        const int slot = k & 7;
        short8 a = abuf[slot];
        if (k + 8 < KOFF)
            abuf[slot] = *(const short8*)(fb + (size_t)(unsigned)enc[k + 8] + boff);

        short8 wb0 = wlds[k * 128 + lane];
        short8 wb1 = wlds[k * 128 + 64 + lane];
        acc0 = __builtin_amdgcn_mfma_f32_16x16x32_bf16(a, wb0, acc0, 0, 0, 0);
        acc1 = __builtin_amdgcn_mfma_f32_16x16x32_bf16(a, wb1, acc1, 0, 0, 0);
    }

    // ---- coalesced epilogue: transpose through LDS, store full 128B rows ----
    __syncthreads();                           // wlds reads done; safe to reuse
    float* tb = (float*)wlds + wave * (16 * 36);   // 16 rows, stride 36

    const float bs0 = bias[m];
    const float bs1 = bias[16 + m];
    if (tv) {
        // C/D layout: col (cout) = lane&15, row (voxel) = quad*4 + reg
#pragma unroll
        for (int r = 0; r < 4; ++r) {
            tb[(quad * 4 + r) * 36 + m]      = acc0[r] + bs0;
            tb[(quad * 4 + r) * 36 + 16 + m] = acc1[r] + bs1;
        }
#pragma unroll
        for (int p = 0; p < 2; ++p) {
            int flat = p * 64 + lane;          // 0..127
            int row  = flat >> 3;              // 8 lanes per 128B row
            int ch   = flat & 7;               // 16B chunk within row
            float4v val = *(const float4v*)(tb + row * 36 + ch * 4);
            *(float4v*)(out + (size_t)(v0 + row) * COUT + ch * 4) = val;
        }
    }
}

extern "C" void kernel_launch(void* const* d_in, const int* in_sizes, int n_in,
                              void* d_out, int out_size, void* d_ws, size_t ws_size,
                              hipStream_t stream) {
    const float* feat = (const float*)d_in[0];
    const float* wgt  = (const float*)d_in[1];
    const float* bias = (const float*)d_in[2];
    const int*   nidx = (const int*)d_in[3];
    const int*   nmsk = (const int*)d_in[4];
    float*       out  = (float*)d_out;

    char* ws = (char*)d_ws;
    unsigned short* fbf   = (unsigned short*)ws;                 // 6,400,064 B
    short8*         wfrag = (short8*)(ws + 6400128);             //    55,296 B

    const int wgt_blocks = (KOFF * 2 * 64 + 255) / 256;          // 14
    cvt_kernel<<<FEAT_BLOCKS + wgt_blocks, 256, 0, stream>>>(feat, wgt, fbf, wfrag);

    const int block = 512;                         // 8 waves = 8 tiles = 128 voxels
    const int grid  = 784;                         // 8 * 98: exact swizzle cover
    subm_conv_kernel<<<grid, block, 0, stream>>>(fbf, wfrag, bias, nidx, nmsk, out);
}